// Round 9
// baseline (47.096 us; speedup 1.0000x reference)
//
#include <hip/hip_runtime.h>
#include <hip/hip_cooperative_groups.h>

namespace cg = cooperative_groups;

#define B_SIZE 16384
#define DIM    128
#define NCLS   100
#define CAP    256                 // per-class row capacity (n_c ~ 164 +- 13)
#define WAVES  8
#define BLK    512
#define SPANSZ (B_SIZE / WAVES)    // 2048 targets per wave
#define WCAP   96                  // per-wave match cap (mean ~20.5, sigma ~4.5)

#define WS_PARTIAL 0               // 128 floats in d_ws

typedef short bf8 __attribute__((ext_vector_type(8)));
typedef float f32x4 __attribute__((ext_vector_type(4)));

__device__ __forceinline__ unsigned bf16_rne(float f) {
    unsigned u = __float_as_uint(f);
    return (u + 0x7FFFu + ((u >> 16) & 1u)) >> 16;
}

// One block per class: membership scan -> LDS bf16 stage -> MFMA pair tiles.
// Cooperative: grid.sync() then block 0 reduces the 100 partials -> out.
__global__ __launch_bounds__(BLK) void fused_kernel(
        const float* __restrict__ x, const int* __restrict__ target,
        float* __restrict__ partials, float* __restrict__ out) {
    __shared__ __align__(16) unsigned short rows[CAP * DIM]; // 64 KB, XOR-swizzled
    __shared__ float nrm[CAP];
    __shared__ int   wreg[WAVES * WCAP];
    __shared__ int   wcnt[WAVES];
    __shared__ int   wbase[WAVES];
    __shared__ int   idxl[CAP];
    __shared__ int   n_sh;
    __shared__ float wsum[WAVES];

    const int c    = blockIdx.x;
    const int tid  = threadIdx.x;
    const int w    = tid >> 6;
    const int lane = tid & 63;

    // ---- phase 1: stable membership list (per-wave span + ballot rank) ----
    {
        int cnt = 0;
        const int base = w * SPANSZ;
        #pragma unroll 4
        for (int i = 0; i < SPANSZ; i += 64) {
            const int j = base + i + lane;
            const bool f = (target[j] == c);
            const unsigned long long m = __ballot(f);
            if (f) {
                const int p = cnt + __popcll(m & ((1ull << lane) - 1ull));
                if (p < WCAP) wreg[w * WCAP + p] = j;
            }
            cnt += __popcll(m);
        }
        if (lane == 0) wcnt[w] = (cnt < WCAP) ? cnt : WCAP;
    }
    __syncthreads();
    if (tid == 0) {
        int a = 0;
        for (int i = 0; i < WAVES; ++i) { wbase[i] = a; a += wcnt[i]; }
        n_sh = (a < CAP) ? a : CAP;
    }
    __syncthreads();
    const int n = n_sh;
    #pragma unroll
    for (int i = 0; i < WAVES; ++i) {
        if (tid < wcnt[i]) {
            const int dst = wbase[i] + tid;
            if (dst < CAP) idxl[dst] = wreg[i * WCAP + tid];
        }
    }
    __syncthreads();

    // ---- phase 2: gather rows -> bf16 LDS (swizzled) + bf16-consistent norms ----
    {
        const int grp = lane >> 4;     // 4 rows in flight per wave
        const int ch  = lane & 15;     // 16B chunk within row
        for (int r = w * 4 + grp; r < n; r += 32) {
            const int idx = idxl[r];
            const float4 v0 = *reinterpret_cast<const float4*>(x + (size_t)idx * DIM + ch * 8);
            const float4 v1 = *reinterpret_cast<const float4*>(x + (size_t)idx * DIM + ch * 8 + 4);
            unsigned b0 = bf16_rne(v0.x), b1 = bf16_rne(v0.y),
                     b2 = bf16_rne(v0.z), b3 = bf16_rne(v0.w);
            unsigned b4 = bf16_rne(v1.x), b5 = bf16_rne(v1.y),
                     b6 = bf16_rne(v1.z), b7 = bf16_rne(v1.w);
            uint4 o;
            o.x = b0 | (b1 << 16); o.y = b2 | (b3 << 16);
            o.z = b4 | (b5 << 16); o.w = b6 | (b7 << 16);
            const int chunk = (r * 16 + ch) ^ (r & 7);
            *reinterpret_cast<uint4*>(&rows[chunk * 8]) = o;

            float c0 = __uint_as_float(b0 << 16), c1 = __uint_as_float(b1 << 16);
            float c2 = __uint_as_float(b2 << 16), c3 = __uint_as_float(b3 << 16);
            float c4 = __uint_as_float(b4 << 16), c5 = __uint_as_float(b5 << 16);
            float c6 = __uint_as_float(b6 << 16), c7 = __uint_as_float(b7 << 16);
            float s = c0*c0 + c1*c1 + c2*c2 + c3*c3 + c4*c4 + c5*c5 + c6*c6 + c7*c7;
            #pragma unroll
            for (int off = 1; off < 16; off <<= 1) s += __shfl_xor(s, off, 64);
            if (ch == 0) nrm[r] = s;
        }
    }
    __syncthreads();

    // ---- phase 3: upper-tri 32x32 MFMA tiles from LDS ----
    float acc = 0.0f;
    if (n > 0) {
        const int T  = (n + 31) >> 5;
        const int nt = T * (T + 1) / 2;
        const int r16 = lane & 15;
        const int kl  = lane >> 4;
        const int last = n - 1;

        for (int t = w; t < nt; t += WAVES) {
            int rem = t, ti = 0;
            while (rem >= T - ti) { rem -= T - ti; ++ti; }
            const int tj = ti + rem;
            const int pb = ti * 32, qb = tj * 32;

            const int pa0 = min(pb + r16, last), pa1 = min(pb + 16 + r16, last);
            const int qa0 = min(qb + r16, last), qa1 = min(qb + 16 + r16, last);

            f32x4 c00 = {0.f,0.f,0.f,0.f}, c01 = {0.f,0.f,0.f,0.f};
            f32x4 c10 = {0.f,0.f,0.f,0.f}, c11 = {0.f,0.f,0.f,0.f};
            #pragma unroll
            for (int ks = 0; ks < 4; ++ks) {
                const int kk = ks * 4 + kl;
                const bf8 a0 = *reinterpret_cast<const bf8*>(&rows[((pa0*16 + kk) ^ (pa0 & 7)) * 8]);
                const bf8 a1 = *reinterpret_cast<const bf8*>(&rows[((pa1*16 + kk) ^ (pa1 & 7)) * 8]);
                const bf8 b0 = *reinterpret_cast<const bf8*>(&rows[((qa0*16 + kk) ^ (qa0 & 7)) * 8]);
                const bf8 b1 = *reinterpret_cast<const bf8*>(&rows[((qa1*16 + kk) ^ (qa1 & 7)) * 8]);
                c00 = __builtin_amdgcn_mfma_f32_16x16x32_bf16(a0, b0, c00, 0, 0, 0);
                c01 = __builtin_amdgcn_mfma_f32_16x16x32_bf16(a0, b1, c01, 0, 0, 0);
                c10 = __builtin_amdgcn_mfma_f32_16x16x32_bf16(a1, b0, c10, 0, 0, 0);
                c11 = __builtin_amdgcn_mfma_f32_16x16x32_bf16(a1, b1, c11, 0, 0, 0);
            }

            const float nb0 = nrm[qa0];
            const float nb1 = nrm[qa1];
            float na[8];
            #pragma unroll
            for (int rg = 0; rg < 2; ++rg)
                #pragma unroll
                for (int r = 0; r < 4; ++r)
                    na[rg * 4 + r] = nrm[min(pb + rg * 16 + kl * 4 + r, last)];

            const bool diag = (ti == tj);
            #pragma unroll
            for (int sub = 0; sub < 4; ++sub) {
                const int rg = sub >> 1, cg = sub & 1;
                const f32x4 cc = (sub == 0) ? c00 : (sub == 1) ? c01 : (sub == 2) ? c10 : c11;
                const int qcol = cg * 16 + r16;
                const float nb = cg ? nb1 : nb0;
                #pragma unroll
                for (int r = 0; r < 4; ++r) {
                    const int prow = rg * 16 + kl * 4 + r;
                    const bool valid = (pb + prow < n) && (qb + qcol < n) &&
                                       (!diag || (prow < qcol));
                    if (valid) {
                        const float d2 = na[rg * 4 + r] + nb - 2.0f * cc[r];
                        acc += sqrtf(fmaxf(d2, 0.0f));
                    }
                }
            }
        }
    }

    // per-wave shuffle reduce, then 8-value finish (replaces 9-level tree)
    #pragma unroll
    for (int off = 1; off < 64; off <<= 1) acc += __shfl_xor(acc, off, 64);
    if (lane == 0) wsum[w] = acc;
    __syncthreads();
    if (tid == 0) {
        float s = 0.0f;
        #pragma unroll
        for (int i = 0; i < WAVES; ++i) s += wsum[i];
        partials[c] = s;
    }

    // ---- grid-wide sync, then block 0 reduces 100 partials ----
    cg::this_grid().sync();
    if (blockIdx.x == 0 && tid < 64) {
        float a = (tid < NCLS) ? partials[tid] : 0.0f;
        if (tid + 64 < NCLS) a += partials[tid + 64];
        #pragma unroll
        for (int off = 1; off < 64; off <<= 1) a += __shfl_xor(a, off, 64);
        if (tid == 0) out[0] = a / (float)B_SIZE;
    }
}

extern "C" void kernel_launch(void* const* d_in, const int* in_sizes, int n_in,
                              void* d_out, int out_size, void* d_ws, size_t ws_size,
                              hipStream_t stream) {
    const float* x      = (const float*)d_in[0];
    const int*   target = (const int*)d_in[1];
    float*       out    = (float*)d_out;
    float*       partials = (float*)((int*)d_ws + WS_PARTIAL);

    void* args[] = { (void*)&x, (void*)&target, (void*)&partials, (void*)&out };
    hipLaunchCooperativeKernel(reinterpret_cast<void*>(fused_kernel),
                               dim3(NCLS), dim3(BLK), args, 0, stream);
}

// Round 10
// 18.165 us; speedup vs baseline: 2.5927x; 2.5927x over previous
//
#include <hip/hip_runtime.h>

#define B_SIZE 16384
#define DIM    128
#define NCLS   100
#define CAP    256                 // per-class row capacity (n_c ~ 164 +- 13; 7 sigma)
#define WAVES  16
#define BLK    1024
#define SPANSZ (B_SIZE / WAVES)    // 1024 targets per wave
#define WCAP   96                  // per-wave match cap (mean ~10.2, sigma ~3.2)

#define WS_PARTIAL 0               // 128 floats in d_ws

typedef short bf8 __attribute__((ext_vector_type(8)));
typedef float f32x4 __attribute__((ext_vector_type(4)));

__device__ __forceinline__ unsigned bf16_rne(float f) {
    unsigned u = __float_as_uint(f);
    return (u + 0x7FFFu + ((u >> 16) & 1u)) >> 16;
}

// One block per class: membership scan -> LDS bf16 stage -> MFMA pair tiles.
// 16 waves/block to halve every phase's serial latency depth vs 8 waves.
__global__ __launch_bounds__(BLK) void class_kernel(
        const float* __restrict__ x, const int* __restrict__ target,
        float* __restrict__ partials) {
    __shared__ __align__(16) unsigned short rows[CAP * DIM]; // 64 KB, XOR-swizzled
    __shared__ float nrm[CAP];
    __shared__ int   wreg[WAVES * WCAP];
    __shared__ int   wcnt[WAVES];
    __shared__ int   wbase[WAVES];
    __shared__ int   idxl[CAP];
    __shared__ int   n_sh;
    __shared__ float wsum[WAVES];

    const int c    = blockIdx.x;
    const int tid  = threadIdx.x;
    const int w    = tid >> 6;
    const int lane = tid & 63;

    // ---- phase 1: stable membership list (per-wave span + ballot rank) ----
    {
        int cnt = 0;
        const int base = w * SPANSZ;
        #pragma unroll 8
        for (int i = 0; i < SPANSZ; i += 64) {
            const int j = base + i + lane;
            const bool f = (target[j] == c);
            const unsigned long long m = __ballot(f);
            if (f) {
                const int p = cnt + __popcll(m & ((1ull << lane) - 1ull));
                if (p < WCAP) wreg[w * WCAP + p] = j;
            }
            cnt += __popcll(m);
        }
        if (lane == 0) wcnt[w] = (cnt < WCAP) ? cnt : WCAP;
    }
    __syncthreads();
    if (tid == 0) {
        int a = 0;
        for (int i = 0; i < WAVES; ++i) { wbase[i] = a; a += wcnt[i]; }
        n_sh = (a < CAP) ? a : CAP;
    }
    __syncthreads();
    const int n = n_sh;
    #pragma unroll
    for (int i = 0; i < WAVES; ++i) {
        if (tid < wcnt[i]) {
            const int dst = wbase[i] + tid;
            if (dst < CAP) idxl[dst] = wreg[i * WCAP + tid];
        }
    }
    __syncthreads();

    // ---- phase 2: gather rows -> bf16 LDS (swizzled) + bf16-consistent norms ----
    {
        const int grp = lane >> 4;     // 4 rows in flight per wave, 64 per block
        const int ch  = lane & 15;     // 16B chunk within row
        for (int r = w * 4 + grp; r < n; r += WAVES * 4) {
            const int idx = idxl[r];
            const float4 v0 = *reinterpret_cast<const float4*>(x + (size_t)idx * DIM + ch * 8);
            const float4 v1 = *reinterpret_cast<const float4*>(x + (size_t)idx * DIM + ch * 8 + 4);
            unsigned b0 = bf16_rne(v0.x), b1 = bf16_rne(v0.y),
                     b2 = bf16_rne(v0.z), b3 = bf16_rne(v0.w);
            unsigned b4 = bf16_rne(v1.x), b5 = bf16_rne(v1.y),
                     b6 = bf16_rne(v1.z), b7 = bf16_rne(v1.w);
            uint4 o;
            o.x = b0 | (b1 << 16); o.y = b2 | (b3 << 16);
            o.z = b4 | (b5 << 16); o.w = b6 | (b7 << 16);
            const int chunk = (r * 16 + ch) ^ (r & 7);
            *reinterpret_cast<uint4*>(&rows[chunk * 8]) = o;

            float c0 = __uint_as_float(b0 << 16), c1 = __uint_as_float(b1 << 16);
            float c2 = __uint_as_float(b2 << 16), c3 = __uint_as_float(b3 << 16);
            float c4 = __uint_as_float(b4 << 16), c5 = __uint_as_float(b5 << 16);
            float c6 = __uint_as_float(b6 << 16), c7 = __uint_as_float(b7 << 16);
            float s = c0*c0 + c1*c1 + c2*c2 + c3*c3 + c4*c4 + c5*c5 + c6*c6 + c7*c7;
            #pragma unroll
            for (int off = 1; off < 16; off <<= 1) s += __shfl_xor(s, off, 64);
            if (ch == 0) nrm[r] = s;
        }
    }
    __syncthreads();

    // ---- phase 3: upper-tri 32x32 MFMA tiles from LDS ----
    float acc = 0.0f;
    if (n > 0) {
        const int T  = (n + 31) >> 5;
        const int nt = T * (T + 1) / 2;
        const int r16 = lane & 15;
        const int kl  = lane >> 4;
        const int last = n - 1;

        for (int t = w; t < nt; t += WAVES) {
            int rem = t, ti = 0;
            while (rem >= T - ti) { rem -= T - ti; ++ti; }
            const int tj = ti + rem;
            const int pb = ti * 32, qb = tj * 32;

            const int pa0 = min(pb + r16, last), pa1 = min(pb + 16 + r16, last);
            const int qa0 = min(qb + r16, last), qa1 = min(qb + 16 + r16, last);

            f32x4 c00 = {0.f,0.f,0.f,0.f}, c01 = {0.f,0.f,0.f,0.f};
            f32x4 c10 = {0.f,0.f,0.f,0.f}, c11 = {0.f,0.f,0.f,0.f};
            #pragma unroll
            for (int ks = 0; ks < 4; ++ks) {
                const int kk = ks * 4 + kl;
                const bf8 a0 = *reinterpret_cast<const bf8*>(&rows[((pa0*16 + kk) ^ (pa0 & 7)) * 8]);
                const bf8 a1 = *reinterpret_cast<const bf8*>(&rows[((pa1*16 + kk) ^ (pa1 & 7)) * 8]);
                const bf8 b0 = *reinterpret_cast<const bf8*>(&rows[((qa0*16 + kk) ^ (qa0 & 7)) * 8]);
                const bf8 b1 = *reinterpret_cast<const bf8*>(&rows[((qa1*16 + kk) ^ (qa1 & 7)) * 8]);
                c00 = __builtin_amdgcn_mfma_f32_16x16x32_bf16(a0, b0, c00, 0, 0, 0);
                c01 = __builtin_amdgcn_mfma_f32_16x16x32_bf16(a0, b1, c01, 0, 0, 0);
                c10 = __builtin_amdgcn_mfma_f32_16x16x32_bf16(a1, b0, c10, 0, 0, 0);
                c11 = __builtin_amdgcn_mfma_f32_16x16x32_bf16(a1, b1, c11, 0, 0, 0);
            }

            const float nb0 = nrm[qa0];
            const float nb1 = nrm[qa1];
            float na[8];
            #pragma unroll
            for (int rg = 0; rg < 2; ++rg)
                #pragma unroll
                for (int r = 0; r < 4; ++r)
                    na[rg * 4 + r] = nrm[min(pb + rg * 16 + kl * 4 + r, last)];

            const bool diag = (ti == tj);
            #pragma unroll
            for (int sub = 0; sub < 4; ++sub) {
                const int rg = sub >> 1, cg = sub & 1;
                const f32x4 cc = (sub == 0) ? c00 : (sub == 1) ? c01 : (sub == 2) ? c10 : c11;
                const int qcol = cg * 16 + r16;
                const float nb = cg ? nb1 : nb0;
                #pragma unroll
                for (int r = 0; r < 4; ++r) {
                    const int prow = rg * 16 + kl * 4 + r;
                    const bool valid = (pb + prow < n) && (qb + qcol < n) &&
                                       (!diag || (prow < qcol));
                    if (valid) {
                        const float d2 = na[rg * 4 + r] + nb - 2.0f * cc[r];
                        acc += sqrtf(fmaxf(d2, 0.0f));
                    }
                }
            }
        }
    }

    // per-wave shuffle reduce, then 16-value finish
    #pragma unroll
    for (int off = 1; off < 64; off <<= 1) acc += __shfl_xor(acc, off, 64);
    if (lane == 0) wsum[w] = acc;
    __syncthreads();
    if (tid == 0) {
        float s = 0.0f;
        #pragma unroll
        for (int i = 0; i < WAVES; ++i) s += wsum[i];
        partials[c] = s;
    }
}

// 100 partials -> scalar
__global__ void reduce_kernel(const float* __restrict__ partials, float* __restrict__ out) {
    const int lane = threadIdx.x;
    float a = (lane < NCLS) ? partials[lane] : 0.0f;
    if (lane + 64 < NCLS) a += partials[lane + 64];
    #pragma unroll
    for (int off = 1; off < 64; off <<= 1) a += __shfl_xor(a, off, 64);
    if (lane == 0) out[0] = a / (float)B_SIZE;
}

extern "C" void kernel_launch(void* const* d_in, const int* in_sizes, int n_in,
                              void* d_out, int out_size, void* d_ws, size_t ws_size,
                              hipStream_t stream) {
    const float* x      = (const float*)d_in[0];
    const int*   target = (const int*)d_in[1];
    float*       out    = (float*)d_out;
    float*       partials = (float*)((int*)d_ws + WS_PARTIAL);

    class_kernel<<<NCLS, BLK, 0, stream>>>(x, target, partials);
    reduce_kernel<<<1, 64, 0, stream>>>(partials, out);
}